// Round 2
// baseline (230.319 us; speedup 1.0000x reference)
//
#include <hip/hip_runtime.h>
#include <hip/hip_bf16.h>

#define NPTS 2048
#define CH 32
#define QT 128
#define LOG2E 1.4426950408889634f

__device__ __forceinline__ float gelu_tanh(float x) {
    // jax.nn.gelu default approximate=True: 0.5x(1+tanh(sqrt(2/pi)(x+0.044715x^3)))
    float x3 = x * x * x;
    float u = 0.7978845608028654f * (x + 0.044715f * x3);
    return 0.5f * x * (1.0f + tanhf(u));
}

// ---------------- lift: fq[n,c] = gelu(f_x[n]*W[c,0] + x[n]*W[c,1] + b[c]) ----------------
__global__ __launch_bounds__(256) void k_lift(const float* __restrict__ f_x,
                                              const float* __restrict__ x_grid,
                                              const float* __restrict__ W,
                                              const float* __restrict__ b,
                                              float* __restrict__ fq) {
    int t = blockIdx.x * 256 + threadIdx.x;
    if (t >= NPTS * CH) return;
    int n = t >> 5, c = t & 31;
    float v = f_x[n] * W[c * 2] + x_grid[n] * W[c * 2 + 1] + b[c];
    fq[t] = gelu_tanh(v);
}

// ---------------- one KNO layer ----------------
// block: 256 thr = 8 rows x 32 channels; grid 256 blocks covers N=2048 rows.
// integ[n,c] = sig2_c * sum_q exp(-(x_n-x_q)^2 / (2 ell2_c)) * fq[q,c] * w[q]
// fq_out = act( fq @ pwW^T + pwb + integ )
__global__ __launch_bounds__(256) void k_layer(const float* __restrict__ fq_in,
                                               float* __restrict__ fq_out,
                                               const float* __restrict__ x_grid,
                                               const float* __restrict__ qw,
                                               const float* __restrict__ pw_W,
                                               const float* __restrict__ pw_b,
                                               const float* __restrict__ log_ell,
                                               const float* __restrict__ log_sig,
                                               int layer, int act) {
    __shared__ float xs[QT];
    __shared__ float gs[QT * CH];

    const int tid = threadIdx.x;
    const int r = tid >> 5;
    const int c = tid & 31;
    const int n = blockIdx.x * 8 + r;

    const float xn = x_grid[n];
    const float ell2 = expf(2.0f * log_ell[layer * CH + c]);
    const float sig2 = expf(2.0f * log_sig[layer * CH + c]);
    const float nb = -LOG2E / (2.0f * ell2);   // exp(-d2/(2 ell2)) = exp2(d2 * nb)

    // skip = fq_in[n,:] . pw_W[layer,c,:] + pw_b[layer,c]
    float skip = pw_b[layer * CH + c];
    const float* Wrow = pw_W + (layer * CH + c) * CH;
    const float* frow = fq_in + n * CH;
#pragma unroll
    for (int k = 0; k < CH; k++) skip = fmaf(frow[k], Wrow[k], skip);

    float acc = 0.0f;
    for (int q0 = 0; q0 < NPTS; q0 += QT) {
        // ---- stage tile: xs[qq], gs[qq*CH+c] = fq_in[q0+qq, c] * w[q0+qq] ----
        if (tid < QT) xs[tid] = x_grid[q0 + tid];
        {
            const int base = tid * 16;  // 16 consecutive f32 per thread; q row = tid>>1
            const float4* src = (const float4*)(fq_in + q0 * CH + base);
            float4 v0 = src[0], v1 = src[1], v2 = src[2], v3 = src[3];
            const float wq = qw[q0 + (tid >> 1)];
            float4* dst = (float4*)(gs + base);
            dst[0] = make_float4(v0.x * wq, v0.y * wq, v0.z * wq, v0.w * wq);
            dst[1] = make_float4(v1.x * wq, v1.y * wq, v1.z * wq, v1.w * wq);
            dst[2] = make_float4(v2.x * wq, v2.y * wq, v2.z * wq, v2.w * wq);
            dst[3] = make_float4(v3.x * wq, v3.y * wq, v3.z * wq, v3.w * wq);
        }
        __syncthreads();

#pragma unroll 8
        for (int qq = 0; qq < QT; qq++) {
            float d = xn - xs[qq];
            float arg = (d * d) * nb;
            float e = exp2f(arg);
            acc = fmaf(e, gs[qq * CH + c], acc);
        }
        __syncthreads();
    }

    float v = skip + sig2 * acc;
    if (act) v = gelu_tanh(v);
    fq_out[n * CH + c] = v;
}

// ---------------- projection head ----------------
__global__ __launch_bounds__(256) void k_proj(const float* __restrict__ fq,
                                              const float* __restrict__ W1,
                                              const float* __restrict__ b1,
                                              const float* __restrict__ W2,
                                              const float* __restrict__ b2,
                                              const float* __restrict__ W3,
                                              const float* __restrict__ b3,
                                              float* __restrict__ out) {
    __shared__ float sW1[CH * CH], sW2[CH * CH], sb1[CH], sb2[CH], sW3[CH];
    const int tid = threadIdx.x;
    for (int i = tid; i < CH * CH; i += 256) { sW1[i] = W1[i]; sW2[i] = W2[i]; }
    if (tid < CH) { sb1[tid] = b1[tid]; sb2[tid] = b2[tid]; sW3[tid] = W3[tid]; }
    __syncthreads();

    const int n = blockIdx.x * 256 + tid;
    float h0[CH], h1[CH];
    const float* row = fq + n * CH;
#pragma unroll
    for (int k = 0; k < CH; k++) h0[k] = row[k];

#pragma unroll
    for (int j = 0; j < CH; j++) {
        float s = sb1[j];
#pragma unroll
        for (int k = 0; k < CH; k++) s = fmaf(h0[k], sW1[j * CH + k], s);
        h1[j] = gelu_tanh(s);
    }
#pragma unroll
    for (int j = 0; j < CH; j++) {
        float s = sb2[j];
#pragma unroll
        for (int k = 0; k < CH; k++) s = fmaf(h1[k], sW2[j * CH + k], s);
        h0[j] = gelu_tanh(s);
    }
    float s = b3[0];
#pragma unroll
    for (int k = 0; k < CH; k++) s = fmaf(h0[k], sW3[k], s);
    out[n] = s;
}

extern "C" void kernel_launch(void* const* d_in, const int* in_sizes, int n_in,
                              void* d_out, int out_size, void* d_ws, size_t ws_size,
                              hipStream_t stream) {
    const float* f_x     = (const float*)d_in[0];
    const float* x_grid  = (const float*)d_in[1];
    const float* qw      = (const float*)d_in[2];
    const float* lift_W  = (const float*)d_in[3];
    const float* lift_b  = (const float*)d_in[4];
    const float* pw_W    = (const float*)d_in[5];
    const float* pw_b    = (const float*)d_in[6];
    const float* kle     = (const float*)d_in[7];
    const float* kls     = (const float*)d_in[8];
    const float* p1W     = (const float*)d_in[9];
    const float* p1b     = (const float*)d_in[10];
    const float* p2W     = (const float*)d_in[11];
    const float* p2b     = (const float*)d_in[12];
    const float* p3W     = (const float*)d_in[13];
    const float* p3b     = (const float*)d_in[14];

    float* fqA = (float*)d_ws;
    float* fqB = fqA + NPTS * CH;

    k_lift<<<NPTS * CH / 256, 256, 0, stream>>>(f_x, x_grid, lift_W, lift_b, fqA);
    k_layer<<<NPTS / 8, 256, 0, stream>>>(fqA, fqB, x_grid, qw, pw_W, pw_b, kle, kls, 0, 1);
    k_layer<<<NPTS / 8, 256, 0, stream>>>(fqB, fqA, x_grid, qw, pw_W, pw_b, kle, kls, 1, 1);
    k_layer<<<NPTS / 8, 256, 0, stream>>>(fqA, fqB, x_grid, qw, pw_W, pw_b, kle, kls, 2, 0);
    k_proj<<<NPTS / 256, 256, 0, stream>>>(fqB, p1W, p1b, p2W, p2b, p3W, p3b,
                                           (float*)d_out);
}

// Round 3
// 209.968 us; speedup vs baseline: 1.0969x; 1.0969x over previous
//
#include <hip/hip_runtime.h>
#include <hip/hip_bf16.h>

#define NPTS 2048
#define CH 32
#define NSEG 8
#define SEGQ (NPTS / NSEG)   // 256
#define LOG2E 1.4426950408889634f

__device__ __forceinline__ float gelu_tanh(float x) {
    float x3 = x * x * x;
    float u = 0.7978845608028654f * (x + 0.044715f * x3);
    return 0.5f * x * (1.0f + tanhf(u));
}

// ---------------- lift: fq[n,c] = gelu(f_x[n]*W[c,0] + x[n]*W[c,1] + b[c]) ----------------
// also writes gt[c][n] = fq[n,c] * w[n]  (transposed, pre-weighted, for layer 0)
__global__ __launch_bounds__(256) void k_lift(const float* __restrict__ f_x,
                                              const float* __restrict__ x_grid,
                                              const float* __restrict__ qw,
                                              const float* __restrict__ W,
                                              const float* __restrict__ b,
                                              float* __restrict__ fq,
                                              float* __restrict__ gt) {
    int t = blockIdx.x * 256 + threadIdx.x;
    if (t >= NPTS * CH) return;
    int n = t >> 5, c = t & 31;
    float v = f_x[n] * W[c * 2] + x_grid[n] * W[c * 2 + 1] + b[c];
    v = gelu_tanh(v);
    fq[t] = v;
    gt[c * NPTS + n] = v * qw[n];
}

// ---------------- one KNO layer ----------------
// block: 512 thr = (2 rows) x (32 ch) x (8 q-segments); grid 1024 blocks.
// integ[n,c] = sig2_c * sum_q exp2(nb_c*(x_n-x_q)^2) * gt[c][q],  nb_c = -log2e/(2 ell2_c)
// arg = A + B*xq + nb*xq^2 with A = nb*xn^2, B = -2 nb xn  (2 fma per q)
__global__ __launch_bounds__(512) void k_layer(const float* __restrict__ fq_in,
                                               const float* __restrict__ gt_in,
                                               float* __restrict__ fq_out,
                                               float* __restrict__ gt_out,
                                               const float* __restrict__ x_grid,
                                               const float* __restrict__ qw,
                                               const float* __restrict__ pw_W,
                                               const float* __restrict__ pw_b,
                                               const float* __restrict__ log_ell,
                                               const float* __restrict__ log_sig,
                                               int layer, int act) {
    __shared__ float xsp[NPTS * 2];            // (xq, xq^2) interleaved, 16 KB
    __shared__ float psum[NSEG * 2 * CH];      // 2 KB

    const int tid = threadIdx.x;
    const int c = tid & 31;
    const int nr = (tid >> 5) & 1;
    const int s = tid >> 6;                    // wave-uniform (64-thread granularity)
    const int n = blockIdx.x * 2 + nr;

    // stage (xq, xq^2) pairs: each thread covers q = 4*tid .. 4*tid+3
    {
        const float4 x4 = ((const float4*)x_grid)[tid];
        float4* dst = (float4*)xsp;
        dst[2 * tid]     = make_float4(x4.x, x4.x * x4.x, x4.y, x4.y * x4.y);
        dst[2 * tid + 1] = make_float4(x4.z, x4.z * x4.z, x4.w, x4.w * x4.w);
    }

    const float xn = x_grid[n];
    const float ell2 = expf(2.0f * log_ell[layer * CH + c]);
    const float nb = -LOG2E / (2.0f * ell2);
    const float A = nb * xn * xn;
    const float B = -2.0f * nb * xn;

    __syncthreads();

    float acc0 = 0.0f, acc1 = 0.0f;
    const float4* gt4 = (const float4*)(gt_in + c * NPTS + s * SEGQ);
    const float4* xp4 = (const float4*)(xsp + 2 * s * SEGQ);
#pragma unroll 8
    for (int i = 0; i < SEGQ / 4; i++) {
        const float4 g  = gt4[i];
        const float4 p0 = xp4[2 * i];          // (xq0, xq0^2, xq1, xq1^2) - broadcast
        const float4 p1 = xp4[2 * i + 1];      // (xq2, xq2^2, xq3, xq3^2)
        acc0 = fmaf(exp2f(fmaf(p0.y, nb, fmaf(p0.x, B, A))), g.x, acc0);
        acc1 = fmaf(exp2f(fmaf(p0.w, nb, fmaf(p0.z, B, A))), g.y, acc1);
        acc0 = fmaf(exp2f(fmaf(p1.y, nb, fmaf(p1.x, B, A))), g.z, acc0);
        acc1 = fmaf(exp2f(fmaf(p1.w, nb, fmaf(p1.z, B, A))), g.w, acc1);
    }
    psum[(s * 2 + nr) * CH + c] = acc0 + acc1;
    __syncthreads();

    // epilogue: 64 threads finish the 2x32 outputs of this block
    if (tid < 64) {
        const int cc = tid & 31, rr = tid >> 5;
        const int nn = blockIdx.x * 2 + rr;
        float sum = 0.0f;
#pragma unroll
        for (int ss = 0; ss < NSEG; ss++) sum += psum[(ss * 2 + rr) * CH + cc];
        const float sig2 = expf(2.0f * log_sig[layer * CH + cc]);
        float skip = pw_b[layer * CH + cc];
        const float* Wrow = pw_W + (layer * CH + cc) * CH;
        const float* frow = fq_in + nn * CH;
#pragma unroll
        for (int k = 0; k < CH; k++) skip = fmaf(frow[k], Wrow[k], skip);
        float v = skip + sig2 * sum;
        if (act) v = gelu_tanh(v);
        fq_out[nn * CH + cc] = v;
        gt_out[cc * NPTS + nn] = v * qw[nn];
    }
}

// ---------------- projection head ----------------
__global__ __launch_bounds__(256) void k_proj(const float* __restrict__ fq,
                                              const float* __restrict__ W1,
                                              const float* __restrict__ b1,
                                              const float* __restrict__ W2,
                                              const float* __restrict__ b2,
                                              const float* __restrict__ W3,
                                              const float* __restrict__ b3,
                                              float* __restrict__ out) {
    __shared__ float sW1[CH * CH], sW2[CH * CH], sb1[CH], sb2[CH], sW3[CH];
    const int tid = threadIdx.x;
    for (int i = tid; i < CH * CH; i += 256) { sW1[i] = W1[i]; sW2[i] = W2[i]; }
    if (tid < CH) { sb1[tid] = b1[tid]; sb2[tid] = b2[tid]; sW3[tid] = W3[tid]; }
    __syncthreads();

    const int n = blockIdx.x * 256 + tid;
    float h0[CH], h1[CH];
    const float* row = fq + n * CH;
#pragma unroll
    for (int k = 0; k < CH; k++) h0[k] = row[k];

#pragma unroll
    for (int j = 0; j < CH; j++) {
        float ss = sb1[j];
#pragma unroll
        for (int k = 0; k < CH; k++) ss = fmaf(h0[k], sW1[j * CH + k], ss);
        h1[j] = gelu_tanh(ss);
    }
#pragma unroll
    for (int j = 0; j < CH; j++) {
        float ss = sb2[j];
#pragma unroll
        for (int k = 0; k < CH; k++) ss = fmaf(h1[k], sW2[j * CH + k], ss);
        h0[j] = gelu_tanh(ss);
    }
    float ss = b3[0];
#pragma unroll
    for (int k = 0; k < CH; k++) ss = fmaf(h0[k], sW3[k], ss);
    out[n] = ss;
}

extern "C" void kernel_launch(void* const* d_in, const int* in_sizes, int n_in,
                              void* d_out, int out_size, void* d_ws, size_t ws_size,
                              hipStream_t stream) {
    const float* f_x     = (const float*)d_in[0];
    const float* x_grid  = (const float*)d_in[1];
    const float* qw      = (const float*)d_in[2];
    const float* lift_W  = (const float*)d_in[3];
    const float* lift_b  = (const float*)d_in[4];
    const float* pw_W    = (const float*)d_in[5];
    const float* pw_b    = (const float*)d_in[6];
    const float* kle     = (const float*)d_in[7];
    const float* kls     = (const float*)d_in[8];
    const float* p1W     = (const float*)d_in[9];
    const float* p1b     = (const float*)d_in[10];
    const float* p2W     = (const float*)d_in[11];
    const float* p2b     = (const float*)d_in[12];
    const float* p3W     = (const float*)d_in[13];
    const float* p3b     = (const float*)d_in[14];

    float* fqA = (float*)d_ws;
    float* fqB = fqA + NPTS * CH;
    float* gtA = fqB + NPTS * CH;
    float* gtB = gtA + NPTS * CH;

    k_lift<<<NPTS * CH / 256, 256, 0, stream>>>(f_x, x_grid, qw, lift_W, lift_b, fqA, gtA);
    k_layer<<<NPTS / 2, 512, 0, stream>>>(fqA, gtA, fqB, gtB, x_grid, qw, pw_W, pw_b, kle, kls, 0, 1);
    k_layer<<<NPTS / 2, 512, 0, stream>>>(fqB, gtB, fqA, gtA, x_grid, qw, pw_W, pw_b, kle, kls, 1, 1);
    k_layer<<<NPTS / 2, 512, 0, stream>>>(fqA, gtA, fqB, gtB, x_grid, qw, pw_W, pw_b, kle, kls, 2, 0);
    k_proj<<<NPTS / 256, 256, 0, stream>>>(fqB, p1W, p1b, p2W, p2b, p3W, p3b,
                                           (float*)d_out);
}

// Round 4
// 102.887 us; speedup vs baseline: 2.2386x; 2.0408x over previous
//
#include <hip/hip_runtime.h>
#include <hip/hip_bf16.h>

#define NPTS 2048
#define CH 32
#define QT 128
#define NSEG 8
#define LOG2E 1.4426950408889634f

#if defined(__has_builtin)
#if __has_builtin(__builtin_amdgcn_exp2f)
#define EXP2F(x) __builtin_amdgcn_exp2f(x)
#endif
#endif
#ifndef EXP2F
#define EXP2F(x) exp2f(x)
#endif

__device__ __forceinline__ float gelu_tanh(float x) {
    float x3 = x * x * x;
    float u = 0.7978845608028654f * (x + 0.044715f * x3);
    return 0.5f * x * (1.0f + tanhf(u));
}

// ---------------- lift: fq[n,c] = gelu(f_x[n]*W[c,0] + x[n]*W[c,1] + b[c]) ----------------
__global__ __launch_bounds__(256) void k_lift(const float* __restrict__ f_x,
                                              const float* __restrict__ x_grid,
                                              const float* __restrict__ W,
                                              const float* __restrict__ b,
                                              float* __restrict__ fq) {
    int t = blockIdx.x * 256 + threadIdx.x;
    if (t >= NPTS * CH) return;
    int n = t >> 5, c = t & 31;
    float v = f_x[n] * W[c * 2] + x_grid[n] * W[c * 2 + 1] + b[c];
    fq[t] = gelu_tanh(v);
}

// ---------------- one KNO layer ----------------
// block: 512 thr = (2 rows) x (32 ch) x (8 q-segments); grid 1024 blocks.
// g tile staged in LDS as [q][CH] (coalesced global read, bank=c conflict-free LDS read).
// arg = nb*(xn-xq)^2 = A + B*xq + nb*xq^2 evaluated Horner: fma(xq, fma(xq,nb,B), A)
__global__ __launch_bounds__(512, 8) void k_layer(const float* __restrict__ fq_in,
                                                  float* __restrict__ fq_out,
                                                  const float* __restrict__ x_grid,
                                                  const float* __restrict__ qw,
                                                  const float* __restrict__ pw_W,
                                                  const float* __restrict__ pw_b,
                                                  const float* __restrict__ log_ell,
                                                  const float* __restrict__ log_sig,
                                                  int layer, int act) {
    __shared__ float xs[NPTS];                 // 8 KB, staged once
    __shared__ float gs[QT * CH];              // 16 KB, per tile
    __shared__ float psum[NSEG * 2 * CH];      // 2 KB

    const int tid = threadIdx.x;
    const int c = tid & 31;
    const int nr = (tid >> 5) & 1;
    const int s = tid >> 6;                    // wave-uniform
    const int n = blockIdx.x * 2 + nr;

    // stage x once: 512 threads x float4 = 2048 floats
    ((float4*)xs)[tid] = ((const float4*)x_grid)[tid];

    const float xn = x_grid[n];
    const float ell2 = expf(2.0f * log_ell[layer * CH + c]);
    const float nb = -LOG2E / (2.0f * ell2);
    const float A = nb * xn * xn;
    const float B = -2.0f * nb * xn;

    const int qq = tid >> 2;                   // 0..127: tile row this thread stages
    const int cb = (tid & 3) * 8;              // 8-float column chunk

    float acc0 = 0.0f, acc1 = 0.0f;
    for (int q0 = 0; q0 < NPTS; q0 += QT) {
        // issue global loads before the barrier (latency overlaps prev consume)
        const float wq = qw[q0 + qq];
        const float4* src = (const float4*)(fq_in + (q0 + qq) * CH + cb);
        const float4 a0 = src[0], a1 = src[1];
        __syncthreads();                       // prev tile fully consumed
        float4* dst = (float4*)(gs + qq * CH + cb);
        dst[0] = make_float4(a0.x * wq, a0.y * wq, a0.z * wq, a0.w * wq);
        dst[1] = make_float4(a1.x * wq, a1.y * wq, a1.z * wq, a1.w * wq);
        __syncthreads();                       // tile visible

        const float* xp = xs + q0 + s * 16;
        const float* gp = gs + (s * 16) * CH + c;
#pragma unroll
        for (int k = 0; k < 4; k++) {
            const float4 x4 = ((const float4*)xp)[k];
            const float g0 = gp[(4 * k + 0) * CH];
            const float g1 = gp[(4 * k + 1) * CH];
            const float g2 = gp[(4 * k + 2) * CH];
            const float g3 = gp[(4 * k + 3) * CH];
            acc0 = fmaf(EXP2F(fmaf(x4.x, fmaf(x4.x, nb, B), A)), g0, acc0);
            acc1 = fmaf(EXP2F(fmaf(x4.y, fmaf(x4.y, nb, B), A)), g1, acc1);
            acc0 = fmaf(EXP2F(fmaf(x4.z, fmaf(x4.z, nb, B), A)), g2, acc0);
            acc1 = fmaf(EXP2F(fmaf(x4.w, fmaf(x4.w, nb, B), A)), g3, acc1);
        }
    }
    psum[(s * 2 + nr) * CH + c] = acc0 + acc1;
    __syncthreads();

    // epilogue: 64 threads finish the 2x32 outputs of this block
    if (tid < 64) {
        const int cc = tid & 31, rr = tid >> 5;
        const int nn = blockIdx.x * 2 + rr;
        float sum = 0.0f;
#pragma unroll
        for (int ss = 0; ss < NSEG; ss++) sum += psum[(ss * 2 + rr) * CH + cc];
        const float sig2 = expf(2.0f * log_sig[layer * CH + cc]);
        float skip = pw_b[layer * CH + cc];
        const float* Wrow = pw_W + (layer * CH + cc) * CH;
        const float* frow = fq_in + nn * CH;
#pragma unroll
        for (int k = 0; k < CH; k++) skip = fmaf(frow[k], Wrow[k], skip);
        float v = skip + sig2 * sum;
        if (act) v = gelu_tanh(v);
        fq_out[nn * CH + cc] = v;
    }
}

// ---------------- projection head ----------------
__global__ __launch_bounds__(256) void k_proj(const float* __restrict__ fq,
                                              const float* __restrict__ W1,
                                              const float* __restrict__ b1,
                                              const float* __restrict__ W2,
                                              const float* __restrict__ b2,
                                              const float* __restrict__ W3,
                                              const float* __restrict__ b3,
                                              float* __restrict__ out) {
    __shared__ float sW1[CH * CH], sW2[CH * CH], sb1[CH], sb2[CH], sW3[CH];
    const int tid = threadIdx.x;
    for (int i = tid; i < CH * CH; i += 256) { sW1[i] = W1[i]; sW2[i] = W2[i]; }
    if (tid < CH) { sb1[tid] = b1[tid]; sb2[tid] = b2[tid]; sW3[tid] = W3[tid]; }
    __syncthreads();

    const int n = blockIdx.x * 256 + tid;
    float h0[CH], h1[CH];
    const float* row = fq + n * CH;
#pragma unroll
    for (int k = 0; k < CH; k++) h0[k] = row[k];

#pragma unroll
    for (int j = 0; j < CH; j++) {
        float ss = sb1[j];
#pragma unroll
        for (int k = 0; k < CH; k++) ss = fmaf(h0[k], sW1[j * CH + k], ss);
        h1[j] = gelu_tanh(ss);
    }
#pragma unroll
    for (int j = 0; j < CH; j++) {
        float ss = sb2[j];
#pragma unroll
        for (int k = 0; k < CH; k++) ss = fmaf(h1[k], sW2[j * CH + k], ss);
        h0[j] = gelu_tanh(ss);
    }
    float ss = b3[0];
#pragma unroll
    for (int k = 0; k < CH; k++) ss = fmaf(h0[k], sW3[k], ss);
    out[n] = ss;
}

extern "C" void kernel_launch(void* const* d_in, const int* in_sizes, int n_in,
                              void* d_out, int out_size, void* d_ws, size_t ws_size,
                              hipStream_t stream) {
    const float* f_x     = (const float*)d_in[0];
    const float* x_grid  = (const float*)d_in[1];
    const float* qw      = (const float*)d_in[2];
    const float* lift_W  = (const float*)d_in[3];
    const float* lift_b  = (const float*)d_in[4];
    const float* pw_W    = (const float*)d_in[5];
    const float* pw_b    = (const float*)d_in[6];
    const float* kle     = (const float*)d_in[7];
    const float* kls     = (const float*)d_in[8];
    const float* p1W     = (const float*)d_in[9];
    const float* p1b     = (const float*)d_in[10];
    const float* p2W     = (const float*)d_in[11];
    const float* p2b     = (const float*)d_in[12];
    const float* p3W     = (const float*)d_in[13];
    const float* p3b     = (const float*)d_in[14];

    float* fqA = (float*)d_ws;
    float* fqB = fqA + NPTS * CH;

    k_lift<<<NPTS * CH / 256, 256, 0, stream>>>(f_x, x_grid, lift_W, lift_b, fqA);
    k_layer<<<NPTS / 2, 512, 0, stream>>>(fqA, fqB, x_grid, qw, pw_W, pw_b, kle, kls, 0, 1);
    k_layer<<<NPTS / 2, 512, 0, stream>>>(fqB, fqA, x_grid, qw, pw_W, pw_b, kle, kls, 1, 1);
    k_layer<<<NPTS / 2, 512, 0, stream>>>(fqA, fqB, x_grid, qw, pw_W, pw_b, kle, kls, 2, 0);
    k_proj<<<NPTS / 256, 256, 0, stream>>>(fqB, p1W, p1b, p2W, p2b, p3W, p3b,
                                           (float*)d_out);
}